// Round 8
// baseline (415.556 us; speedup 1.0000x reference)
//
#include <hip/hip_runtime.h>

#define LBL 64
#define SEQN 512
#define BATCHN 512
#define START_ID 62
#define PAD_ID 63
#define CH 4            // steps per chunk; renorm every 8 steps (t0%8==0, tt==0)

// 256 blocks x 64 threads (1 wave). Each wave advances TWO chains on
// DISJOINT pipes: chain0 via v_readlane->SGPR->FMA (VALU/SALU), chain1 via
// ds_swizzle broadcast->VGPR->FMA (DS pipe). The two chains' instruction
// streams are independent, so each fills the other's latency bubbles.
// Linear-space recurrence A <- (A . expT) * exp(e); renorm every 8 steps via
// exact power-of-2 scale from the exponent field.
__global__ __launch_bounds__(64) void crf_batch_kernel(
    const float* __restrict__ ts,      // [B,S,L]
    const float* __restrict__ T,       // [L,L]
    const int*   __restrict__ labels,  // [B,S]
    const int*   __restrict__ lengths, // [B]
    float*       __restrict__ ws)      // [B] out: fwd_b - gold_b
{
  const int b0 = blockIdx.x;
  const int b1 = b0 + (BATCHN / 2);
  const int j = threadIdx.x;  // 0..63
  const int len0 = lengths[b0];
  const int len1 = lengths[b1];
  const float* __restrict__ e0 = ts + (size_t)b0 * SEQN * LBL;
  const float* __restrict__ e1 = ts + (size_t)b1 * SEQN * LBL;
  const int* __restrict__ lab0 = labels + b0 * SEQN;
  const int* __restrict__ lab1 = labels + b1 * SEQN;

  // Chain0 coefficients: straight order c0[i] = exp(T[i][j]).
  float c0[LBL];
#pragma unroll
  for (int i = 0; i < LBL; ++i) c0[i] = __expf(T[i * LBL + j]);

  // Chain1 coefficients: half-relative order for ds_swizzle consumption.
  // Phase-1 swizzle k delivers A[k + half]; phase 2 (after half-swap)
  // delivers A[k + (half^32)].
  const int half = j & 32;
  float c1[32], c2[32];
#pragma unroll
  for (int k = 0; k < 32; ++k) {
    c1[k] = __expf(T[(k + half) * LBL + j]);
    c2[k] = __expf(T[(k + (half ^ 32)) * LBL + j]);
  }
  const float expPad = __expf(T[j * LBL + PAD_ID]);
  const int swap_addr = (j ^ 32) << 2;  // ds_bpermute byte index (lane j^32)

  // Emission buffers: raw loads 2 chunks (8 steps) ahead, exp at rotate.
  float eC0[CH], eN0[CH], eC1[CH], eN1[CH];
#pragma unroll
  for (int r = 0; r < CH; ++r) {
    eC0[r] = __expf(e0[r * LBL + j]);
    eC1[r] = __expf(e1[r * LBL + j]);
  }
#pragma unroll
  for (int r = 0; r < CH; ++r) {
    eN0[r] = e0[(CH + r) * LBL + j];
    eN1[r] = e1[(CH + r) * LBL + j];
  }

  float A0 = __expf(e0[j] + T[START_ID * LBL + j]);
  float A1 = __expf(e1[j] + T[START_ID * LBL + j]);
  int E0 = 0, E1 = 0;  // stored = true * 2^E

  const int lenmax = (len0 > len1) ? len0 : len1;

  for (int t0 = 0; t0 < lenmax; t0 += CH) {
    const bool renorm_chunk = ((t0 & 7) == 0);  // wave-uniform
#pragma unroll
    for (int tt = 0; tt < CH; ++tt) {
      const int t = t0 + tt;
      const bool act0 = (t >= 1) && (t < len0);
      const bool act1 = (t >= 1) && (t < len1);
      const bool renorm = renorm_chunk && (tt == 0);
      if (act0 || act1) {
        // ---- chain1: issue DS broadcast ops first (DS pipe churns) ----
        const int A1b = __float_as_int(A1);
        const int A1s = __builtin_amdgcn_ds_bpermute(swap_addr, A1b);
        float bc[64];
#define SWZ_PAIR(K)                                                              \
        bc[K]      = __int_as_float(__builtin_amdgcn_ds_swizzle(A1b, (K) << 5)); \
        bc[32+(K)] = __int_as_float(__builtin_amdgcn_ds_swizzle(A1s, (K) << 5));
        SWZ_PAIR(0)  SWZ_PAIR(1)  SWZ_PAIR(2)  SWZ_PAIR(3)
        SWZ_PAIR(4)  SWZ_PAIR(5)  SWZ_PAIR(6)  SWZ_PAIR(7)
        SWZ_PAIR(8)  SWZ_PAIR(9)  SWZ_PAIR(10) SWZ_PAIR(11)
        SWZ_PAIR(12) SWZ_PAIR(13) SWZ_PAIR(14) SWZ_PAIR(15)
        SWZ_PAIR(16) SWZ_PAIR(17) SWZ_PAIR(18) SWZ_PAIR(19)
        SWZ_PAIR(20) SWZ_PAIR(21) SWZ_PAIR(22) SWZ_PAIR(23)
        SWZ_PAIR(24) SWZ_PAIR(25) SWZ_PAIR(26) SWZ_PAIR(27)
        SWZ_PAIR(28) SWZ_PAIR(29) SWZ_PAIR(30) SWZ_PAIR(31)
#undef SWZ_PAIR

        // ---- chain0: readlane phase -> SGPR block ----
        const int A0b = __float_as_int(A0);
        int sg[LBL];
#pragma unroll
        for (int k = 0; k < LBL; ++k) sg[k] = __builtin_amdgcn_readlane(A0b, k);

        __builtin_amdgcn_sched_barrier(0);  // pin phase structure

        // ---- chain0 FMAs (SGPR broadcast operand) ----
        float s00 = 0.f, s01 = 0.f, s02 = 0.f, s03 = 0.f;
#pragma unroll
        for (int k = 0; k < LBL; k += 4) {
          s00 = fmaf(__int_as_float(sg[k + 0]), c0[k + 0], s00);
          s01 = fmaf(__int_as_float(sg[k + 1]), c0[k + 1], s01);
          s02 = fmaf(__int_as_float(sg[k + 2]), c0[k + 2], s02);
          s03 = fmaf(__int_as_float(sg[k + 3]), c0[k + 3], s03);
        }

        // ---- chain1 FMAs (bc operands; granular lgkmcnt) ----
        float s10 = 0.f, s11 = 0.f, s12 = 0.f, s13 = 0.f;
#pragma unroll
        for (int k = 0; k < 32; k += 4) {
          s10 = fmaf(bc[k + 0], c1[k + 0], s10);
          s11 = fmaf(bc[k + 1], c1[k + 1], s11);
          s12 = fmaf(bc[k + 2], c1[k + 2], s12);
          s13 = fmaf(bc[k + 3], c1[k + 3], s13);
        }
#pragma unroll
        for (int k = 0; k < 32; k += 4) {
          s10 = fmaf(bc[32 + k + 0], c2[k + 0], s10);
          s11 = fmaf(bc[32 + k + 1], c2[k + 1], s11);
          s12 = fmaf(bc[32 + k + 2], c2[k + 2], s12);
          s13 = fmaf(bc[32 + k + 3], c2[k + 3], s13);
        }

        float ex0 = eC0[tt], ex1 = eC1[tt];
        if (renorm) {
          // chain0: SALU umax tree over SGPR block (A>0 -> uint compare ok)
          unsigned m[32];
#pragma unroll
          for (int k = 0; k < 32; ++k) {
            const unsigned a = (unsigned)sg[k], bu = (unsigned)sg[k + 32];
            m[k] = a > bu ? a : bu;
          }
#pragma unroll
          for (int st = 16; st >= 1; st >>= 1)
#pragma unroll
            for (int k = 0; k < 16; ++k)
              if (k < st) m[k] = m[k] > m[k + st] ? m[k] : m[k + st];
          const unsigned em0 = (m[0] >> 23) & 255u;
          ex0 *= __uint_as_float((254u - em0) << 23);  // * 2^(127-em), exact
          E0 += act0 ? (127 - (int)em0) : 0;

          // chain1: VALU fmax tree over bc (wave-uniform values)
          float fm[32];
#pragma unroll
          for (int k = 0; k < 32; ++k) fm[k] = fmaxf(bc[k], bc[32 + k]);
#pragma unroll
          for (int st = 16; st >= 1; st >>= 1)
#pragma unroll
            for (int k = 0; k < 16; ++k)
              if (k < st) fm[k] = fmaxf(fm[k], fm[k + st]);
          const unsigned em1 = (__float_as_uint(fm[0]) >> 23) & 255u;
          ex1 *= __uint_as_float((254u - em1) << 23);
          E1 += act1 ? (127 - (int)em1) : 0;
        }
        const float nA0 = ((s00 + s01) + (s02 + s03)) * ex0;
        const float nA1 = ((s10 + s11) + (s12 + s13)) * ex1;
        A0 = act0 ? nA0 : A0;
        A1 = act1 ? nA1 : A1;
      }
    }

    // rotate (exp now: loads are 8 steps old -> latency hidden) + prefetch
#pragma unroll
    for (int r = 0; r < CH; ++r) {
      eC0[r] = __expf(eN0[r]);
      eC1[r] = __expf(eN1[r]);
    }
    const int tb = (t0 + 2 * CH <= SEQN - CH) ? (t0 + 2 * CH) : (SEQN - CH);
#pragma unroll
    for (int r = 0; r < CH; ++r) {
      eN0[r] = e0[(tb + r) * LBL + j];
      eN1[r] = e1[(tb + r) * LBL + j];
    }
  }

  // ---- gold path scores (lane-strided over t) ----
  float g0 = 0.0f, g1 = 0.0f;
  for (int t = j; t < len0; t += 64) {
    const int l = lab0[t];
    const int prev = (t == 0) ? START_ID : lab0[t - 1];
    g0 += T[prev * LBL + l] + e0[t * LBL + l];
  }
  for (int t = j; t < len1; t += 64) {
    const int l = lab1[t];
    const int prev = (t == 0) ? START_ID : lab1[t - 1];
    g1 += T[prev * LBL + l] + e1[t * LBL + l];
  }

  // ---- final logsumexp + wave reductions ----
  float v0 = A0 * expPad;
  float v1 = A1 * expPad;
#pragma unroll
  for (int d = 1; d < 64; d <<= 1) {
    v0 += __shfl_xor(v0, d);
    g0 += __shfl_xor(g0, d);
    v1 += __shfl_xor(v1, d);
    g1 += __shfl_xor(g1, d);
  }

  if (j == 0) {
    const float ln2 = 0.69314718055994531f;
    ws[b0] = (logf(v0) - (float)E0 * ln2) - (g0 + T[lab0[len0 - 1] * LBL + PAD_ID]);
    ws[b1] = (logf(v1) - (float)E1 * ln2) - (g1 + T[lab1[len1 - 1] * LBL + PAD_ID]);
  }
}

__global__ __launch_bounds__(256) void crf_reduce_kernel(
    const float* __restrict__ ws, float* __restrict__ out)
{
  __shared__ float red[4];
  const int tid = threadIdx.x;  // 256 threads
  float v = ws[tid] + ws[tid + 256];
#pragma unroll
  for (int d = 1; d < 64; d <<= 1) v += __shfl_xor(v, d);
  if ((tid & 63) == 0) red[tid >> 6] = v;
  __syncthreads();
  if (tid == 0) out[0] = (red[0] + red[1] + red[2] + red[3]) * (1.0f / BATCHN);
}

extern "C" void kernel_launch(void* const* d_in, const int* in_sizes, int n_in,
                              void* d_out, int out_size, void* d_ws, size_t ws_size,
                              hipStream_t stream) {
  const float* ts      = (const float*)d_in[0];
  const float* T       = (const float*)d_in[1];
  const int*   labels  = (const int*)d_in[2];
  const int*   lengths = (const int*)d_in[3];
  float* out = (float*)d_out;
  float* ws  = (float*)d_ws;

  crf_batch_kernel<<<BATCHN / 2, 64, 0, stream>>>(ts, T, labels, lengths, ws);
  crf_reduce_kernel<<<1, 256, 0, stream>>>(ws, out);
}

// Round 9
// 213.620 us; speedup vs baseline: 1.9453x; 1.9453x over previous
//
#include <hip/hip_runtime.h>

#define LBL 64
#define SEQN 512
#define BATCHN 512
#define START_ID 62
#define PAD_ID 63
#define CH 8            // steps per chunk; renorm at tt==0 (every 8th step)

// One block per batch element, 64 threads = 1 wave. Lane j owns label-state j.
// Linear-space recurrence A <- (A . expT) * exp(e).
// Broadcast via v_readlane software-pipelined 8 ahead of the consuming FMA:
// readlane(k+8) issues, FMA(k) consumes sg[k] written 16 issue-cycles ago ->
// SGPR hazard covered, every FMA overlaps an independent readlane.
// sched_barrier(0) after each pair pins the interleave (emits no ISA).
// Renorm every 8 steps via SALU umax tree (A>0 -> uint compare) off-path.
__global__ __launch_bounds__(64) void crf_batch_kernel(
    const float* __restrict__ ts,      // [B,S,L]
    const float* __restrict__ T,       // [L,L]
    const int*   __restrict__ labels,  // [B,S]
    const int*   __restrict__ lengths, // [B]
    float*       __restrict__ ws)      // [B] out: fwd_b - gold_b
{
  const int b = blockIdx.x;
  const int j = threadIdx.x;  // 0..63
  const int len = lengths[b];
  const float* __restrict__ e_b = ts + (size_t)b * SEQN * LBL;
  const int* __restrict__ lab_b = labels + b * SEQN;

  // expT column j in registers: c[i] = exp(T[i][j]). Coalesced loads.
  float c[LBL];
#pragma unroll
  for (int i = 0; i < LBL; ++i) c[i] = __expf(T[i * LBL + j]);
  const float expPad = __expf(T[j * LBL + PAD_ID]);  // exp(T[j, PAD])

  // Emission buffers: raw loads (latency hidden over 8 steps), exp at rotate.
  float eC[CH], eNraw[CH];
#pragma unroll
  for (int r = 0; r < CH; ++r) eC[r] = __expf(e_b[r * LBL + j]);
#pragma unroll
  for (int r = 0; r < CH; ++r) eNraw[r] = e_b[(CH + r) * LBL + j];

  float A = __expf(e_b[j] + T[START_ID * LBL + j]);  // alpha0, linear space
  int E = 0;  // stored = true * 2^E (exact power-of-2 bookkeeping)

  for (int t0 = 0; t0 < len; t0 += CH) {
#pragma unroll
    for (int tt = 0; tt < CH; ++tt) {
      const int t = t0 + tt;
      const bool act = (t >= 1) && (t < len);  // wave-uniform, branchless use
      const int Ab = __float_as_int(A);

      int sg[LBL];
      // ---- prologue: fill the 8-deep readlane window ----
#pragma unroll
      for (int k = 0; k < 8; ++k) sg[k] = __builtin_amdgcn_readlane(Ab, k);
      __builtin_amdgcn_sched_barrier(0);

      // ---- steady state: readlane(k+8) || FMA(k), pinned alternation ----
      float s0 = 0.f, s1 = 0.f, s2 = 0.f, s3 = 0.f;
#pragma unroll
      for (int k = 0; k < LBL; ++k) {
        if (k < LBL - 8) sg[k + 8] = __builtin_amdgcn_readlane(Ab, k + 8);
        const float av = __int_as_float(sg[k]);
        if ((k & 3) == 0)      s0 = fmaf(av, c[k], s0);
        else if ((k & 3) == 1) s1 = fmaf(av, c[k], s1);
        else if ((k & 3) == 2) s2 = fmaf(av, c[k], s2);
        else                   s3 = fmaf(av, c[k], s3);
        __builtin_amdgcn_sched_barrier(0);
      }

      float ex = eC[tt];
      if (tt == 0) {  // renorm: SALU umax tree over SGPR block, off-path
        unsigned m[32];
#pragma unroll
        for (int k = 0; k < 32; ++k) {
          const unsigned a = (unsigned)sg[k], bu = (unsigned)sg[k + 32];
          m[k] = a > bu ? a : bu;
        }
#pragma unroll
        for (int st = 16; st >= 1; st >>= 1)
#pragma unroll
          for (int k = 0; k < 16; ++k)
            if (k < st) m[k] = m[k] > m[k + st] ? m[k] : m[k + st];
        const unsigned em = (m[0] >> 23) & 255u;
        ex *= __uint_as_float((254u - em) << 23);  // * 2^(127-em), exact
        E += act ? (127 - (int)em) : 0;
      }
      const float nA = ((s0 + s1) + (s2 + s3)) * ex;
      A = act ? nA : A;  // branchless guard (NaN past len discarded)
    }

    // rotate (exp now: loads are 8 steps old -> latency hidden) + prefetch
#pragma unroll
    for (int r = 0; r < CH; ++r) eC[r] = __expf(eNraw[r]);
    const int tb = (t0 + 2 * CH <= SEQN - CH) ? (t0 + 2 * CH) : (SEQN - CH);
#pragma unroll
    for (int r = 0; r < CH; ++r) eNraw[r] = e_b[(tb + r) * LBL + j];
  }

  // ---- gold path score (lane-strided over t) ----
  float g = 0.0f;
  for (int t = j; t < len; t += 64) {
    const int l = lab_b[t];
    const int prev = (t == 0) ? START_ID : lab_b[t - 1];
    g += T[prev * LBL + l] + e_b[t * LBL + l];
  }

  // ---- final logsumexp + wave reductions ----
  float v = A * expPad;
#pragma unroll
  for (int d = 1; d < 64; d <<= 1) {
    v += __shfl_xor(v, d);
    g += __shfl_xor(g, d);
  }

  if (j == 0) {
    const int last = lab_b[len - 1];
    const float gold = g + T[last * LBL + PAD_ID];
    const float fwd = logf(v) - (float)E * 0.69314718055994531f;
    ws[b] = fwd - gold;
  }
}

__global__ __launch_bounds__(256) void crf_reduce_kernel(
    const float* __restrict__ ws, float* __restrict__ out)
{
  __shared__ float red[4];
  const int tid = threadIdx.x;  // 256 threads
  float v = ws[tid] + ws[tid + 256];
#pragma unroll
  for (int d = 1; d < 64; d <<= 1) v += __shfl_xor(v, d);
  if ((tid & 63) == 0) red[tid >> 6] = v;
  __syncthreads();
  if (tid == 0) out[0] = (red[0] + red[1] + red[2] + red[3]) * (1.0f / BATCHN);
}

extern "C" void kernel_launch(void* const* d_in, const int* in_sizes, int n_in,
                              void* d_out, int out_size, void* d_ws, size_t ws_size,
                              hipStream_t stream) {
  const float* ts      = (const float*)d_in[0];
  const float* T       = (const float*)d_in[1];
  const int*   labels  = (const int*)d_in[2];
  const int*   lengths = (const int*)d_in[3];
  float* out = (float*)d_out;
  float* ws  = (float*)d_ws;

  crf_batch_kernel<<<BATCHN, 64, 0, stream>>>(ts, T, labels, lengths, ws);
  crf_reduce_kernel<<<1, 256, 0, stream>>>(ws, out);
}